// Round 6
// baseline (190.600 us; speedup 1.0000x reference)
//
#include <hip/hip_runtime.h>
#include <math.h>

#define NT    300
#define NA    3
#define BATCH 16
#define NCLS  80
#define CCH   85
#define NROWS 2700            // 3 layers * 900 rows (a*NT+ti)
#define NBLK  394             // obj blocks: 300 (L0) + 75 (L1) + 19 (L2); also host target waves
#define NWAVE (NBLK * 4)      // 1576 waves; each handles rows gw and gw+1576
#define HASHSZ 4096

// ws layout (byte offsets) — every slot written unconditionally by main_kernel,
// so NO pre-zeroing (and no memset dispatch) is needed:
//   0     : double obj_part[394]      per-obj-block softplus partial
//   3200  : float4 row_data[2700]     {lbox, lcls, nval, scatter_val}
//   46400 : int    row_key [2700]     (-1 masked; else (li<<20)|cell, cell<2^19)

__device__ __forceinline__ float softplusf(float x) {
    // == max(x,0) + log1p(exp(-|x|)) == bce(x, 0)
    return fmaxf(x, 0.f) + log1pf(expf(-fabsf(x)));
}

// 256-thread block reduce; result valid on thread 0
__device__ __forceinline__ double block_reduce256(double v, double* red) {
    #pragma unroll
    for (int off = 32; off > 0; off >>= 1) v += __shfl_down(v, off, 64);
    const int wid = threadIdx.x >> 6, lane = threadIdx.x & 63;
    if (lane == 0) red[wid] = v;
    __syncthreads();
    double r = (threadIdx.x < 4) ? red[threadIdx.x] : 0.0;
    r += __shfl_down(r, 2, 64);
    r += __shfl_down(r, 1, 64);
    __syncthreads();
    return r;
}

// 1024-thread block reduce; result valid on thread 0
__device__ __forceinline__ double block_reduce1024(double v, double* red) {
    #pragma unroll
    for (int off = 32; off > 0; off >>= 1) v += __shfl_down(v, off, 64);
    const int wid = threadIdx.x >> 6, lane = threadIdx.x & 63;
    if (lane == 0) red[wid] = v;
    __syncthreads();
    double r = (threadIdx.x < 16) ? red[threadIdx.x] : 0.0;
    #pragma unroll
    for (int off = 8; off > 0; off >>= 1) r += __shfl_down(r, off, 64);
    __syncthreads();
    return r;
}

__global__ __launch_bounds__(256) void main_kernel(
    const float* __restrict__ p0, const float* __restrict__ p1,
    const float* __restrict__ p2,
    const float* __restrict__ targets, const float* __restrict__ anchors,
    char* __restrict__ ws)
{
    __shared__ double red[4];

    double* obj_part = (double*)(ws);
    float4* row_data = (float4*)(ws + 3200);
    int*    row_key  = (int*)(ws + 46400);

    // ---------- phase 1: obj softplus sweep (4 independent loads/thread) ----
    {
        const int ob = blockIdx.x;
        int li, bb;
        if (ob < 300)      { li = 0; bb = ob; }
        else if (ob < 375) { li = 1; bb = ob - 300; }
        else               { li = 2; bb = ob - 375; }
        const float* p = (li == 0) ? p0 : ((li == 1) ? p1 : p2);
        const int N = (BATCH * NA * 6400) >> (2*li);   // 307200/76800/19200

        float s = 0.f;
        #pragma unroll
        for (int k = 0; k < 4; ++k) {
            const int idx = bb * 1024 + k * 256 + threadIdx.x;
            if (idx < N) s += softplusf(p[(size_t)idx * CCH + 4]);
        }
        const double t = block_reduce256((double)s, red);
        if (threadIdx.x == 0) obj_part[ob] = t;
    }

    // ---------- phase 2: per-target math, ONE ROW PER WAVE -------------------
    const int gw   = blockIdx.x * 4 + (threadIdx.x >> 6);   // global wave id
    const int lane = threadIdx.x & 63;

    #pragma unroll
    for (int rr = 0; rr < 2; ++rr) {
        const int gr = gw + rr * NWAVE;                     // global row
        if (gr >= NROWS) break;
        const int li = gr / (NA * NT);
        const int r  = gr - li * (NA * NT);                 // a*NT + ti
        const int a  = r / NT;
        const int ti = r - a * NT;
        const float* p = (li == 0) ? p0 : ((li == 1) ? p1 : p2);
        const int W = 80 >> li, H = W;

        // wave-uniform scalars (broadcast loads)
        const float img = targets[ti*6 + 0];
        const float cls = targets[ti*6 + 1];
        const float tx  = targets[ti*6 + 2] * (float)W;
        const float ty  = targets[ti*6 + 3] * (float)H;
        const float tw  = targets[ti*6 + 4] * (float)W;
        const float th  = targets[ti*6 + 5] * (float)H;

        const float ax = anchors[(li*3 + a)*2 + 0];
        const float ay = anchors[(li*3 + a)*2 + 1];
        const float rx = tw / ax, ry = th / ay;
        const float mr = fmaxf(fmaxf(rx, 1.f/rx), fmaxf(ry, 1.f/ry));
        const bool  mask = mr < 4.f;
        const float mf = mask ? 1.f : 0.f;

        const int b = (int)img;
        const int c = (int)cls;
        const int gij_x = (int)tx;      // trunc == floor (positive)
        const int gij_y = (int)ty;
        const int gi = min(max(gij_x, 0), W - 1);
        const int gj = min(max(gij_y, 0), H - 1);

        // reference quirk: anch = anchors[a, a] (layer-independent)
        const float anch_x = anchors[(a*3 + a)*2 + 0];
        const float anch_y = anchors[(a*3 + a)*2 + 1];

        const int match = BATCH - 1 - b;
        const int cell  = ((match*NA + a)*H + gj)*W + gi;
        const float* ps = p + (size_t)cell * CCH;

        // coalesced: 2 wave-load instructions cover all 85 channels
        const float x1 = ps[lane];                                // ch 0..63
        const float x2 = (lane < CCH - 64) ? ps[64 + lane] : 0.f; // ch 64..84

        const float s0   = __shfl(x1, 0);
        const float s1   = __shfl(x1, 1);
        const float s2   = __shfl(x1, 2);
        const float s3   = __shfl(x1, 3);
        const float objx = __shfl(x1, 4);

        // cls: sum_k softplus(ps[5+k]) - ps[5+c]
        const int ch = 5 + c;
        float contrib = (lane >= 5) ? softplusf(x1) : 0.f;
        if (lane < CCH - 64) contrib += softplusf(x2);
        if (lane == ch) contrib -= x1;
        if (ch >= 64 && lane == ch - 64) contrib -= x2;
        #pragma unroll
        for (int off = 32; off > 0; off >>= 1)
            contrib += __shfl_down(contrib, off, 64);             // lane 0 has sum

        // box math (wave-uniform)
        const float pxx = 1.f / (1.f + expf(-s0));
        const float pyy = 1.f / (1.f + expf(-s1));
        const float pw  = expf(s2) * anch_x;
        const float ph  = expf(s3) * anch_y;
        const float fx  = tx - (float)gij_x;
        const float fy  = ty - (float)gij_y;

        const float eps = 1e-9f;
        const float b1x1 = pxx - pw*0.5f, b1x2 = pxx + pw*0.5f;
        const float b1y1 = pyy - ph*0.5f, b1y2 = pyy + ph*0.5f;
        const float b2x1 = fx - tw*0.5f,  b2x2 = fx + tw*0.5f;
        const float b2y1 = fy - th*0.5f,  b2y2 = fy + th*0.5f;
        float iw = fminf(b1x2, b2x2) - fmaxf(b1x1, b2x1); iw = fmaxf(iw, 0.f);
        float ih = fminf(b1y2, b2y2) - fmaxf(b1y1, b2y1); ih = fmaxf(ih, 0.f);
        const float inter = iw * ih;
        const float w1 = b1x2 - b1x1, h1 = b1y2 - b1y1 + eps;
        const float w2 = b2x2 - b2x1, h2 = b2y2 - b2y1 + eps;
        const float uni = w1*h1 + w2*h2 - inter + eps;
        const float iou = inter / uni;
        const float cw  = fmaxf(b1x2, b2x2) - fminf(b1x1, b2x1);
        const float chh = fmaxf(b1y2, b2y2) - fminf(b1y1, b2y1);
        const float c2 = cw*cw + chh*chh + eps;
        const float dx = b2x1 + b2x2 - b1x1 - b1x2;
        const float dy = b2y1 + b2y2 - b1y1 - b1y2;
        const float rho2 = (dx*dx + dy*dy) * 0.25f;
        const float dat = atanf(w2/h2) - atanf(w1/h1);
        const float v = 0.40528473456935108577f * dat * dat;      // 4/pi^2
        const float alpha = v / (1.f + eps - iou + v);
        const float ciou = iou - (rho2/c2 + v*alpha);

        if (lane == 0) {
            row_data[gr] = make_float4((1.f - ciou) * mf,
                                       contrib * mf,
                                       mf,
                                       mask ? objx * fmaxf(ciou, 0.f) : 0.f);
            row_key[gr]  = mask ? ((li << 20) | cell) : -1;
        }
    }
}

__global__ __launch_bounds__(1024) void final_kernel(
    const char* __restrict__ ws, float* __restrict__ out)
{
    __shared__ double red[16];
    __shared__ int hkey[HASHSZ];
    __shared__ int hrow[HASHSZ];

    const double* obj_part = (const double*)(ws);
    const float4* row_data = (const float4*)(ws + 3200);
    const int*    row_key  = (const int*)(ws + 46400);

    for (int q = threadIdx.x; q < HASHSZ; q += 1024) { hkey[q] = -1; hrow[q] = -1; }
    __syncthreads();

    // obj softplus sums per layer (394 < 1024: single pass)
    double so[3] = {0, 0, 0};
    if (threadIdx.x < NBLK) {
        const double v = obj_part[threadIdx.x];
        if (threadIdx.x < 300)      so[0] = v;
        else if (threadIdx.x < 375) so[1] = v;
        else                        so[2] = v;
    }

    // row sums + last-wins hash insert
    int    slots[3];
    float4 rdat[3];
    int    nm = 0;
    double lb[3] = {0,0,0}, lc[3] = {0,0,0}, nv[3] = {0,0,0}, co[3] = {0,0,0};

    for (int i = threadIdx.x; i < NROWS; i += 1024) {
        const int l = i / (NA * NT);
        const float4 d = row_data[i];
        rdat[nm] = d;
        lb[l] += (double)d.x;
        lc[l] += (double)d.y;
        nv[l] += (double)d.z;
        const int k = row_key[i];
        int s = -1;
        if (k >= 0) {
            unsigned h = ((unsigned)k * 2654435761u) >> 20;
            s = (int)(h & (HASHSZ - 1));
            while (true) {
                const int prev = atomicCAS(&hkey[s], -1, k);
                if (prev == -1 || prev == k) { atomicMax(&hrow[s], i); break; }
                s = (s + 1) & (HASHSZ - 1);
            }
        }
        slots[nm++] = s;
    }
    __syncthreads();
    nm = 0;
    for (int i = threadIdx.x; i < NROWS; i += 1024) {
        const int s = slots[nm];
        if (s >= 0 && hrow[s] == i)          // last-wins winner of its cell
            co[i / (NA * NT)] += (double)rdat[nm].w;
        ++nm;
    }

    double rsum[12];
    #pragma unroll
    for (int l = 0; l < 3; ++l) {
        rsum[l*4 + 0] = block_reduce1024(lb[l], red);
        rsum[l*4 + 1] = block_reduce1024(lc[l], red);
        rsum[l*4 + 2] = block_reduce1024(co[l], red);
        rsum[l*4 + 3] = block_reduce1024(nv[l], red);
        so[l]         = block_reduce1024(so[l], red);
    }

    if (threadIdx.x == 0) {
        double lbox = 0.0, lobj = 0.0, lcls = 0.0;
        for (int l = 0; l < 3; ++l) {
            const double nvv = fmax(rsum[l*4 + 3], 1.0);
            lbox += rsum[l*4 + 0] / nvv;
            lcls += rsum[l*4 + 1] / (nvv * (double)NCLS);
            const double N = (double)((BATCH * NA * 6400) >> (2*l));
            lobj += (so[l] - rsum[l*4 + 2]) / N;
        }
        lbox *= 0.05;
        lcls *= 0.5;
        const double loss = lbox + lobj + lcls;
        out[0] = (float)loss;
        out[1] = (float)lbox;
        out[2] = (float)lobj;
        out[3] = (float)lcls;
        out[4] = (float)loss;
    }
}

extern "C" void kernel_launch(void* const* d_in, const int* in_sizes, int n_in,
                              void* d_out, int out_size, void* d_ws, size_t ws_size,
                              hipStream_t stream) {
    const float* p0      = (const float*)d_in[0];
    const float* p1      = (const float*)d_in[1];
    const float* p2      = (const float*)d_in[2];
    const float* targets = (const float*)d_in[3];
    const float* anchors = (const float*)d_in[4];

    main_kernel<<<NBLK, 256, 0, stream>>>(p0, p1, p2, targets, anchors,
                                          (char*)d_ws);
    final_kernel<<<1, 1024, 0, stream>>>((const char*)d_ws, (float*)d_out);
}

// Round 7
// 188.268 us; speedup vs baseline: 1.0124x; 1.0124x over previous
//
#include <hip/hip_runtime.h>
#include <math.h>

#define NT    300
#define NA    3
#define BATCH 16
#define NCLS  80
#define CCH   85
#define NROWS 2700            // 3 layers * 900 rows (a*NT+ti)
#define NBO   788             // obj blocks @512 elems: 600 (L0) + 150 (L1) + 38 (L2)
#define NBT   675             // target blocks: 4 waves/block, one ROW per WAVE
#define NBLK  (NBO + NBT)
#define HASHSZ 4096

// ws layout (byte offsets) — every slot written unconditionally by main_kernel,
// so NO pre-zeroing (and no memset dispatch) is needed:
//   0     : double obj_part[788]      per-obj-block softplus partial
//   6400  : float4 row_data[2700]     {lbox, lcls, nval, scatter_val}
//   49600 : int    row_key [2700]     (-1 masked; else (li<<20)|cell, cell<2^19)

__device__ __forceinline__ float softplusf(float x) {
    // == max(x,0) + log1p(exp(-|x|)) == bce(x, 0)
    return fmaxf(x, 0.f) + log1pf(expf(-fabsf(x)));
}

// 256-thread block reduce; result valid on thread 0
__device__ __forceinline__ double block_reduce256(double v, double* red) {
    #pragma unroll
    for (int off = 32; off > 0; off >>= 1) v += __shfl_down(v, off, 64);
    const int wid = threadIdx.x >> 6, lane = threadIdx.x & 63;
    if (lane == 0) red[wid] = v;
    __syncthreads();
    double r = (threadIdx.x < 4) ? red[threadIdx.x] : 0.0;
    r += __shfl_down(r, 2, 64);
    r += __shfl_down(r, 1, 64);
    __syncthreads();
    return r;
}

// 1024-thread block reduce; result valid on thread 0
__device__ __forceinline__ double block_reduce1024(double v, double* red) {
    #pragma unroll
    for (int off = 32; off > 0; off >>= 1) v += __shfl_down(v, off, 64);
    const int wid = threadIdx.x >> 6, lane = threadIdx.x & 63;
    if (lane == 0) red[wid] = v;
    __syncthreads();
    double r = (threadIdx.x < 16) ? red[threadIdx.x] : 0.0;
    #pragma unroll
    for (int off = 8; off > 0; off >>= 1) r += __shfl_down(r, off, 64);
    __syncthreads();
    return r;
}

__global__ __launch_bounds__(256) void main_kernel(
    const float* __restrict__ p0, const float* __restrict__ p1,
    const float* __restrict__ p2,
    const float* __restrict__ targets, const float* __restrict__ anchors,
    char* __restrict__ ws)
{
    __shared__ double red[4];

    double* obj_part = (double*)(ws);
    float4* row_data = (float4*)(ws + 6400);
    int*    row_key  = (int*)(ws + 49600);

    if (blockIdx.x < NBO) {
        // ---------- obj softplus sweep: 512 elems/block, 2 loads/thread ------
        const int ob = blockIdx.x;
        int li, bb;
        if (ob < 600)      { li = 0; bb = ob; }
        else if (ob < 750) { li = 1; bb = ob - 600; }
        else               { li = 2; bb = ob - 750; }
        const float* p = (li == 0) ? p0 : ((li == 1) ? p1 : p2);
        const int N = (BATCH * NA * 6400) >> (2*li);   // 307200/76800/19200

        float s = 0.f;
        #pragma unroll
        for (int k = 0; k < 2; ++k) {
            const int idx = bb * 512 + k * 256 + threadIdx.x;
            if (idx < N) s += softplusf(p[(size_t)idx * CCH + 4]);
        }
        const double t = block_reduce256((double)s, red);
        if (threadIdx.x == 0) obj_part[ob] = t;
        return;
    }

    // ---------- per-target math: ONE ROW PER WAVE (coalesced 85-ch load) ----
    const int gr   = (blockIdx.x - NBO) * 4 + (threadIdx.x >> 6); // global row
    const int lane = threadIdx.x & 63;
    const int li   = gr / (NA * NT);
    const int r    = gr - li * (NA * NT);                   // a*NT + ti
    const int a    = r / NT;
    const int ti   = r - a * NT;
    const float* p = (li == 0) ? p0 : ((li == 1) ? p1 : p2);
    const int W = 80 >> li, H = W;

    // wave-uniform scalars (broadcast loads)
    const float img = targets[ti*6 + 0];
    const float cls = targets[ti*6 + 1];
    const float tx  = targets[ti*6 + 2] * (float)W;
    const float ty  = targets[ti*6 + 3] * (float)H;
    const float tw  = targets[ti*6 + 4] * (float)W;
    const float th  = targets[ti*6 + 5] * (float)H;

    const float ax = anchors[(li*3 + a)*2 + 0];
    const float ay = anchors[(li*3 + a)*2 + 1];
    const float rx = tw / ax, ry = th / ay;
    const float mr = fmaxf(fmaxf(rx, 1.f/rx), fmaxf(ry, 1.f/ry));
    const bool  mask = mr < 4.f;
    const float mf = mask ? 1.f : 0.f;

    const int b = (int)img;
    const int c = (int)cls;
    const int gij_x = (int)tx;          // trunc == floor (positive)
    const int gij_y = (int)ty;
    const int gi = min(max(gij_x, 0), W - 1);
    const int gj = min(max(gij_y, 0), H - 1);

    // reference quirk: anch = anchors[a, a] (layer-independent)
    const float anch_x = anchors[(a*3 + a)*2 + 0];
    const float anch_y = anchors[(a*3 + a)*2 + 1];

    const int match = BATCH - 1 - b;
    const int cell  = ((match*NA + a)*H + gj)*W + gi;
    const float* ps = p + (size_t)cell * CCH;

    // coalesced: 2 wave-load instructions cover all 85 channels
    const float x1 = ps[lane];                                // ch 0..63
    const float x2 = (lane < CCH - 64) ? ps[64 + lane] : 0.f; // ch 64..84

    const float s0   = __shfl(x1, 0);
    const float s1   = __shfl(x1, 1);
    const float s2   = __shfl(x1, 2);
    const float s3   = __shfl(x1, 3);
    const float objx = __shfl(x1, 4);

    // cls: sum_k softplus(ps[5+k]) - ps[5+c]
    const int ch = 5 + c;
    float contrib = (lane >= 5) ? softplusf(x1) : 0.f;
    if (lane < CCH - 64) contrib += softplusf(x2);
    if (lane == ch) contrib -= x1;
    if (ch >= 64 && lane == ch - 64) contrib -= x2;
    #pragma unroll
    for (int off = 32; off > 0; off >>= 1)
        contrib += __shfl_down(contrib, off, 64);             // lane 0 has sum

    // box math (wave-uniform)
    const float pxx = 1.f / (1.f + expf(-s0));
    const float pyy = 1.f / (1.f + expf(-s1));
    const float pw  = expf(s2) * anch_x;
    const float ph  = expf(s3) * anch_y;
    const float fx  = tx - (float)gij_x;
    const float fy  = ty - (float)gij_y;

    const float eps = 1e-9f;
    const float b1x1 = pxx - pw*0.5f, b1x2 = pxx + pw*0.5f;
    const float b1y1 = pyy - ph*0.5f, b1y2 = pyy + ph*0.5f;
    const float b2x1 = fx - tw*0.5f,  b2x2 = fx + tw*0.5f;
    const float b2y1 = fy - th*0.5f,  b2y2 = fy + th*0.5f;
    float iw = fminf(b1x2, b2x2) - fmaxf(b1x1, b2x1); iw = fmaxf(iw, 0.f);
    float ih = fminf(b1y2, b2y2) - fmaxf(b1y1, b2y1); ih = fmaxf(ih, 0.f);
    const float inter = iw * ih;
    const float w1 = b1x2 - b1x1, h1 = b1y2 - b1y1 + eps;
    const float w2 = b2x2 - b2x1, h2 = b2y2 - b2y1 + eps;
    const float uni = w1*h1 + w2*h2 - inter + eps;
    const float iou = inter / uni;
    const float cw  = fmaxf(b1x2, b2x2) - fminf(b1x1, b2x1);
    const float chh = fmaxf(b1y2, b2y2) - fminf(b1y1, b2y1);
    const float c2 = cw*cw + chh*chh + eps;
    const float dx = b2x1 + b2x2 - b1x1 - b1x2;
    const float dy = b2y1 + b2y2 - b1y1 - b1y2;
    const float rho2 = (dx*dx + dy*dy) * 0.25f;
    const float dat = atanf(w2/h2) - atanf(w1/h1);
    const float v = 0.40528473456935108577f * dat * dat;      // 4/pi^2
    const float alpha = v / (1.f + eps - iou + v);
    const float ciou = iou - (rho2/c2 + v*alpha);

    if (lane == 0) {
        row_data[gr] = make_float4((1.f - ciou) * mf,
                                   contrib * mf,
                                   mf,
                                   mask ? objx * fmaxf(ciou, 0.f) : 0.f);
        row_key[gr]  = mask ? ((li << 20) | cell) : -1;
    }
}

__global__ __launch_bounds__(1024) void final_kernel(
    const char* __restrict__ ws, float* __restrict__ out)
{
    __shared__ double red[16];
    __shared__ int hkey[HASHSZ];
    __shared__ int hrow[HASHSZ];

    const double* obj_part = (const double*)(ws);
    const float4* row_data = (const float4*)(ws + 6400);
    const int*    row_key  = (const int*)(ws + 49600);

    for (int q = threadIdx.x; q < HASHSZ; q += 1024) { hkey[q] = -1; hrow[q] = -1; }
    __syncthreads();

    // obj softplus sums per layer (788 entries, 1024 threads: single pass)
    double so[3] = {0, 0, 0};
    if (threadIdx.x < NBO) {
        const double v = obj_part[threadIdx.x];
        if (threadIdx.x < 600)      so[0] = v;
        else if (threadIdx.x < 750) so[1] = v;
        else                        so[2] = v;
    }

    // row sums + last-wins hash insert
    int    slots[3];
    float4 rdat[3];
    int    nm = 0;
    double lb[3] = {0,0,0}, lc[3] = {0,0,0}, nv[3] = {0,0,0}, co[3] = {0,0,0};

    for (int i = threadIdx.x; i < NROWS; i += 1024) {
        const int l = i / (NA * NT);
        const float4 d = row_data[i];
        rdat[nm] = d;
        lb[l] += (double)d.x;
        lc[l] += (double)d.y;
        nv[l] += (double)d.z;
        const int k = row_key[i];
        int s = -1;
        if (k >= 0) {
            unsigned h = ((unsigned)k * 2654435761u) >> 20;
            s = (int)(h & (HASHSZ - 1));
            while (true) {
                const int prev = atomicCAS(&hkey[s], -1, k);
                if (prev == -1 || prev == k) { atomicMax(&hrow[s], i); break; }
                s = (s + 1) & (HASHSZ - 1);
            }
        }
        slots[nm++] = s;
    }
    __syncthreads();
    nm = 0;
    for (int i = threadIdx.x; i < NROWS; i += 1024) {
        const int s = slots[nm];
        if (s >= 0 && hrow[s] == i)          // last-wins winner of its cell
            co[i / (NA * NT)] += (double)rdat[nm].w;
        ++nm;
    }

    double rsum[12];
    #pragma unroll
    for (int l = 0; l < 3; ++l) {
        rsum[l*4 + 0] = block_reduce1024(lb[l], red);
        rsum[l*4 + 1] = block_reduce1024(lc[l], red);
        rsum[l*4 + 2] = block_reduce1024(co[l], red);
        rsum[l*4 + 3] = block_reduce1024(nv[l], red);
        so[l]         = block_reduce1024(so[l], red);
    }

    if (threadIdx.x == 0) {
        double lbox = 0.0, lobj = 0.0, lcls = 0.0;
        for (int l = 0; l < 3; ++l) {
            const double nvv = fmax(rsum[l*4 + 3], 1.0);
            lbox += rsum[l*4 + 0] / nvv;
            lcls += rsum[l*4 + 1] / (nvv * (double)NCLS);
            const double N = (double)((BATCH * NA * 6400) >> (2*l));
            lobj += (so[l] - rsum[l*4 + 2]) / N;
        }
        lbox *= 0.05;
        lcls *= 0.5;
        const double loss = lbox + lobj + lcls;
        out[0] = (float)loss;
        out[1] = (float)lbox;
        out[2] = (float)lobj;
        out[3] = (float)lcls;
        out[4] = (float)loss;
    }
}

extern "C" void kernel_launch(void* const* d_in, const int* in_sizes, int n_in,
                              void* d_out, int out_size, void* d_ws, size_t ws_size,
                              hipStream_t stream) {
    const float* p0      = (const float*)d_in[0];
    const float* p1      = (const float*)d_in[1];
    const float* p2      = (const float*)d_in[2];
    const float* targets = (const float*)d_in[3];
    const float* anchors = (const float*)d_in[4];

    main_kernel<<<NBLK, 256, 0, stream>>>(p0, p1, p2, targets, anchors,
                                          (char*)d_ws);
    final_kernel<<<1, 1024, 0, stream>>>((const char*)d_ws, (float*)d_out);
}